// Round 1
// baseline (149.887 us; speedup 1.0000x reference)
//
#include <hip/hip_runtime.h>

#define NNODES 8192
#define NEDGES 16384
#define DD 128
#define RR 64
#define BB 16
#define CAP 512          // per-relation sorted-edge capacity (max expected ~310)
#define ETILES 16        // 16 tiles * 32 edges = 512 = CAP

// ws layout (floats):
//   fw    : [FW_OFF,   +RR*DD*DD)   combined relation weights [64][128][128]
//   counts: [CNT_OFF,  +NNODES*RR)  per-(tgt,rel) edge counts
//   swT   : [SWT_OFF,  +DD*DD)      self_weight transposed
//   sortE : [SORT_OFF, +RR*CAP)     edge ids, fixed-stride segments per relation (as int)
//   relN  : [RELN_OFF, +RR)         edges per relation (as int)
#define FW_OFF   0
#define CNT_OFF  (RR*DD*DD)
#define SWT_OFF  (CNT_OFF + NNODES*RR)
#define SORT_OFF (SWT_OFF + DD*DD)
#define RELN_OFF (SORT_OFF + RR*CAP)

// blocks [0,1024): fw (float4-vectorized basis combination)
// blocks [1024,1040): swT transpose
// blocks [1040,1104): per-(tgt,rel) count atomics (counts pre-zeroed by memset)
// blocks [1104,1168): per-relation edge compaction (counting sort, fixed segments)
__global__ __launch_bounds__(256) void prep_kernel(
    const float* __restrict__ weight,      // [16,128,128]
    const float* __restrict__ w_comp,      // [64,16]
    const float* __restrict__ self_weight, // [128,128]
    const int* __restrict__ deprel,
    const int* __restrict__ edge_index,
    float* __restrict__ ws) {
  __shared__ int scnt;
  const int tid = threadIdx.x, bid = blockIdx.x;
  if (bid < 1024) {
    int g = bid * 256 + tid;          // float4 index, 4096 per relation
    int r = g >> 12;
    int ij4 = g & 4095;
    const float4* w4 = reinterpret_cast<const float4*>(weight);
    float4 acc = {0.f, 0.f, 0.f, 0.f};
#pragma unroll
    for (int b = 0; b < BB; ++b) {
      float c = w_comp[r * BB + b];
      float4 v = w4[b * 4096 + ij4];
      acc.x += c * v.x; acc.y += c * v.y; acc.z += c * v.z; acc.w += c * v.w;
    }
    reinterpret_cast<float4*>(ws + FW_OFF)[g] = acc;
  } else if (bid < 1040) {
    // swT[i][j] = self_weight[j][i]; thread handles (j, i0..i0+3): coalesced read
    int idx = (bid - 1024) * 256 + tid;    // 0..4095
    int j = idx >> 5, i0 = (idx & 31) * 4;
    float4 v = *reinterpret_cast<const float4*>(self_weight + j * DD + i0);
    ws[SWT_OFF + (i0 + 0) * DD + j] = v.x;
    ws[SWT_OFF + (i0 + 1) * DD + j] = v.y;
    ws[SWT_OFF + (i0 + 2) * DD + j] = v.z;
    ws[SWT_OFF + (i0 + 3) * DD + j] = v.w;
  } else if (bid < 1104) {
    int e = (bid - 1040) * 256 + tid;
    int rel = deprel[e];
    int tgt = edge_index[NEDGES + e];
    atomicAdd(ws + CNT_OFF + tgt * RR + rel, 1.0f);
  } else {
    int r = bid - 1104;
    if (tid == 0) scnt = 0;
    __syncthreads();
    int* sortE = reinterpret_cast<int*>(ws + SORT_OFF) + r * CAP;
    for (int e = tid; e < NEDGES; e += 256) {
      if (deprel[e] == r) {
        int p = atomicAdd(&scnt, 1);
        if (p < CAP) sortE[p] = e;
      }
    }
    __syncthreads();
    if (tid == 0)
      reinterpret_cast<int*>(ws + RELN_OFF)[r] = (scnt < CAP ? scnt : CAP);
  }
}

// Unified GEMM kernel: blocks [0, RR*ETILES) = edge tiles (32 edges each),
// blocks [RR*ETILES, +NNODES/32) = self-projection tiles (32 nodes each).
// Weight matrix (64 KB) staged in LDS; inner loop is pure LDS+VALU.
__global__ __launch_bounds__(256) void fused_kernel(
    const float* __restrict__ inp,
    const int* __restrict__ edge_index,
    const float* __restrict__ bias,
    const float* __restrict__ ws,
    float* __restrict__ out) {
  __shared__ __align__(16) float fwS[DD * DD];   // 64 KB staged weights [i][j]
  __shared__ __align__(16) float xs[DD * 32];    // 16 KB x-tile [i][m], pre-scaled
  const int tid = threadIdx.x, bid = blockIdx.x;

  const int* sortE = reinterpret_cast<const int*>(ws + SORT_OFF);
  const int* relN  = reinterpret_cast<const int*>(ws + RELN_OFF);

  const bool is_edge = bid < RR * ETILES;
  int r = 0, base = 0, nrem = 32, n0 = 0;
  const float* wsrc;
  if (is_edge) {
    r = bid >> 4;
    base = (bid & (ETILES - 1)) * 32;
    int cnt = relN[r];
    if (base >= cnt) return;              // block-uniform early exit
    nrem = min(32, cnt - base);
    wsrc = ws + FW_OFF + r * DD * DD;
  } else {
    n0 = (bid - RR * ETILES) * 32;
    wsrc = ws + SWT_OFF;
  }

  // --- issue per-edge header chain first (dependent L2 loads), so the
  // independent weight-staging loads below overlap its latency ---
  const int m = tid & 31, ih = tid >> 5;
  int srow; float scale;
  if (is_edge) {
    if (m < nrem) {
      int e = sortE[r * CAP + base + m];
      srow = edge_index[e];
      int tgt = edge_index[NEDGES + e];
      scale = 1.0f / ws[CNT_OFF + tgt * RR + r];
    } else { srow = 0; scale = 0.0f; }
  } else { srow = n0 + m; scale = 1.0f; }

  // --- stage weights: 64 KB, coalesced float4, linear LDS ---
  {
    const float4* s4 = reinterpret_cast<const float4*>(wsrc);
    float4* d4 = reinterpret_cast<float4*>(fwS);
#pragma unroll 4
    for (int k = tid; k < DD * DD / 4; k += 256) d4[k] = s4[k];
  }

  // --- stage x-tile (scaled): xs[i][m] ---
  {
    const float4* srcp = reinterpret_cast<const float4*>(inp + srow * DD + ih * 16);
#pragma unroll
    for (int k = 0; k < 4; ++k) {
      float4 v = srcp[k];
      int i = ih * 16 + k * 4;
      xs[(i + 0) * 32 + m] = v.x * scale;
      xs[(i + 1) * 32 + m] = v.y * scale;
      xs[(i + 2) * 32 + m] = v.z * scale;
      xs[(i + 3) * 32 + m] = v.w * scale;
    }
  }
  __syncthreads();

  // --- 32x128 = [32 rows] x [128x128] matmul, 4x4 register tile ---
  const int jq = tid & 31, mg = tid >> 5;
  const int j0 = jq * 4, m0 = mg * 4;
  float acc[4][4] = {};
#pragma unroll 4
  for (int i = 0; i < DD; ++i) {
    float4 x4 = *reinterpret_cast<const float4*>(&xs[i * 32 + m0]);
    float4 w4 = *reinterpret_cast<const float4*>(&fwS[i * DD + j0]);
    acc[0][0] += x4.x * w4.x; acc[0][1] += x4.x * w4.y; acc[0][2] += x4.x * w4.z; acc[0][3] += x4.x * w4.w;
    acc[1][0] += x4.y * w4.x; acc[1][1] += x4.y * w4.y; acc[1][2] += x4.y * w4.z; acc[1][3] += x4.y * w4.w;
    acc[2][0] += x4.z * w4.x; acc[2][1] += x4.z * w4.y; acc[2][2] += x4.z * w4.z; acc[2][3] += x4.z * w4.w;
    acc[3][0] += x4.w * w4.x; acc[3][1] += x4.w * w4.y; acc[3][2] += x4.w * w4.z; acc[3][3] += x4.w * w4.w;
  }

  // --- scatter ---
  if (is_edge) {
#pragma unroll
    for (int mi = 0; mi < 4; ++mi) {
      int mm = m0 + mi;
      if (mm < nrem) {
        int e = sortE[r * CAP + base + mm];
        int tgt = edge_index[NEDGES + e];
        float* orow = out + tgt * DD + j0;
        atomicAdd(&orow[0], acc[mi][0]);
        atomicAdd(&orow[1], acc[mi][1]);
        atomicAdd(&orow[2], acc[mi][2]);
        atomicAdd(&orow[3], acc[mi][3]);
      }
    }
  } else {
    float4 b4 = *reinterpret_cast<const float4*>(bias + j0);
#pragma unroll
    for (int mi = 0; mi < 4; ++mi) {
      float* orow = out + (n0 + m0 + mi) * DD + j0;
      atomicAdd(&orow[0], acc[mi][0] + b4.x);
      atomicAdd(&orow[1], acc[mi][1] + b4.y);
      atomicAdd(&orow[2], acc[mi][2] + b4.z);
      atomicAdd(&orow[3], acc[mi][3] + b4.w);
    }
  }
}

extern "C" void kernel_launch(void* const* d_in, const int* in_sizes, int n_in,
                              void* d_out, int out_size, void* d_ws, size_t ws_size,
                              hipStream_t stream) {
  const float* inp        = (const float*)d_in[0];
  const int*   deprel     = (const int*)d_in[1];
  const int*   edge_index = (const int*)d_in[2];
  const float* weight     = (const float*)d_in[3];
  const float* w_comp     = (const float*)d_in[4];
  const float* self_w     = (const float*)d_in[5];
  const float* bias       = (const float*)d_in[6];
  float* out = (float*)d_out;
  float* ws  = (float*)d_ws;

  hipMemsetAsync(ws + CNT_OFF, 0, (size_t)NNODES * RR * sizeof(float), stream);
  hipMemsetAsync(out, 0, (size_t)NNODES * DD * sizeof(float), stream);
  prep_kernel<<<1168, 256, 0, stream>>>(weight, w_comp, self_w, deprel, edge_index, ws);
  fused_kernel<<<RR * ETILES + NNODES / 32, 256, 0, stream>>>(inp, edge_index, bias, ws, out);
}

// Round 2
// 142.023 us; speedup vs baseline: 1.0554x; 1.0554x over previous
//
#include <hip/hip_runtime.h>

#define NNODES 8192
#define NEDGES 16384
#define DD 128
#define RR 64
#define BB 16
#define CAP 512          // per-relation sorted-edge capacity (max expected ~300)
#define ET 22            // 16-edge tiles per relation (covers up to 352 edges/rel)

// ws layout (floats):
//   fw    : [FW_OFF,   +RR*DD*DD)     combined relation weights [64][128][128]
//   counts: [CNT_OFF,  +NNODES*RR)    per-(tgt,rel) edge counts (f32)
//   relN  : [RELN_OFF, +RR)           per-relation edge count / sort cursor (int)
//   swT   : [SWT_OFF,  +DD*DD)        self_weight transposed
//   sortE : [SORT_OFF, +RR*CAP)       edge ids, fixed-stride per-relation segments (int)
#define FW_OFF   0
#define CNT_OFF  (RR*DD*DD)
#define RELN_OFF (CNT_OFF + NNODES*RR)
#define SWT_OFF  (RELN_OFF + RR)
#define SORT_OFF (SWT_OFF + DD*DD)

// prep phases by blockIdx:
//   [0,1024)    : fw basis combination (float4)
//   [1024,1040) : swT transpose
//   [1040,1104) : edge counting-sort (LDS histogram) + per-(tgt,rel) count atomics
//   [1104,2128) : zero out[] (float4)
__global__ __launch_bounds__(256) void prep_kernel(
    const float* __restrict__ weight,      // [16,128,128]
    const float* __restrict__ w_comp,      // [64,16]
    const float* __restrict__ self_weight, // [128,128]
    const int* __restrict__ deprel,
    const int* __restrict__ edge_index,
    float* __restrict__ ws,
    float* __restrict__ out) {
  const int tid = threadIdx.x, bid = blockIdx.x;
  if (bid < 1024) {
    int g = bid * 256 + tid;          // float4 index, 4096 per relation
    int r = g >> 12;
    int ij4 = g & 4095;
    const float4* w4 = reinterpret_cast<const float4*>(weight);
    float4 acc = {0.f, 0.f, 0.f, 0.f};
#pragma unroll
    for (int b = 0; b < BB; ++b) {
      float c = w_comp[r * BB + b];
      float4 v = w4[b * 4096 + ij4];
      acc.x += c * v.x; acc.y += c * v.y; acc.z += c * v.z; acc.w += c * v.w;
    }
    reinterpret_cast<float4*>(ws + FW_OFF)[g] = acc;
  } else if (bid < 1040) {
    int idx = (bid - 1024) * 256 + tid;    // 0..4095
    int j = idx >> 5, i0 = (idx & 31) * 4;
    float4 v = *reinterpret_cast<const float4*>(self_weight + j * DD + i0);
    ws[SWT_OFF + (i0 + 0) * DD + j] = v.x;
    ws[SWT_OFF + (i0 + 1) * DD + j] = v.y;
    ws[SWT_OFF + (i0 + 2) * DD + j] = v.z;
    ws[SWT_OFF + (i0 + 3) * DD + j] = v.w;
  } else if (bid < 1104) {
    __shared__ int hist[RR];
    __shared__ int bse[RR];
    int e = (bid - 1040) * 256 + tid;
    int r = deprel[e];
    int t = edge_index[NEDGES + e];
    if (tid < RR) hist[tid] = 0;
    __syncthreads();
    atomicAdd(&hist[r], 1);
    atomicAdd(ws + CNT_OFF + t * RR + r, 1.0f);   // counts pre-zeroed by memset
    __syncthreads();
    int* relN = reinterpret_cast<int*>(ws + RELN_OFF);
    if (tid < RR) { bse[tid] = atomicAdd(&relN[tid], hist[tid]); hist[tid] = 0; }
    __syncthreads();
    int p = bse[r] + atomicAdd(&hist[r], 1);
    if (p < CAP) reinterpret_cast<int*>(ws + SORT_OFF)[r * CAP + p] = e;
  } else {
    int g = (bid - 1104) * 256 + tid;      // float4 index over out (262144 total)
    float4 z = {0.f, 0.f, 0.f, 0.f};
    reinterpret_cast<float4*>(out)[g] = z;
  }
}

// Unified GEMM: blocks [0, RR*ET) = 16-edge tiles; [RR*ET, +NNODES/16) = 16-node
// self tiles. No weight staging: w4 streamed from L2/L3 (L1 broadcasts the row).
// LDS = 8 KB x-tile only -> occupancy limited by wave supply, not LDS.
__global__ __launch_bounds__(256) void gemm_kernel(
    const float* __restrict__ inp,
    const int* __restrict__ edge_index,
    const float* __restrict__ bias,
    const float* __restrict__ ws,
    float* __restrict__ out) {
  __shared__ __align__(16) float xs[DD * 16];   // xs[i][m], pre-scaled
  __shared__ int tqs[16];
  __shared__ int sqs[16];
  __shared__ float cqs[16];
  const int tid = threadIdx.x, bid = blockIdx.x;
  const int* relN  = reinterpret_cast<const int*>(ws + RELN_OFF);
  const int* sortE = reinterpret_cast<const int*>(ws + SORT_OFF);

  const bool is_edge = bid < RR * ET;
  int r = 0, base = 0, nrem = 16, n0 = 0;
  const float* wsrc;
  if (is_edge) {
    r = bid / ET;
    base = (bid - r * ET) * 16;
    int cnt = relN[r];
    cnt = min(cnt, ET * 16);
    if (base >= cnt) return;              // block-uniform early exit
    nrem = min(16, cnt - base);
    wsrc = ws + FW_OFF + r * DD * DD;
  } else {
    n0 = (bid - RR * ET) * 16;
    wsrc = ws + SWT_OFF;
  }

  if (tid < 16) {
    int s = 0, t = 0; float c = 0.f;
    if (is_edge) {
      if (tid < nrem) {
        int e = sortE[r * CAP + base + tid];
        s = edge_index[e];
        t = edge_index[NEDGES + e];
        c = 1.0f / ws[CNT_OFF + t * RR + r];
      }
    } else { s = n0 + tid; t = n0 + tid; c = 1.0f; }
    sqs[tid] = s; tqs[tid] = t; cqs[tid] = c;
  }
  __syncthreads();

  {
    int m = tid & 15, ih = tid >> 4;      // 16 lanes x 16 i-chunks of 8
    int s = sqs[m]; float c = cqs[m];
    const float4* sp = reinterpret_cast<const float4*>(inp + s * DD + ih * 8);
    float4 v0 = sp[0], v1 = sp[1];
    int i0 = ih * 8;
    xs[(i0 + 0) * 16 + m] = v0.x * c; xs[(i0 + 1) * 16 + m] = v0.y * c;
    xs[(i0 + 2) * 16 + m] = v0.z * c; xs[(i0 + 3) * 16 + m] = v0.w * c;
    xs[(i0 + 4) * 16 + m] = v1.x * c; xs[(i0 + 5) * 16 + m] = v1.y * c;
    xs[(i0 + 6) * 16 + m] = v1.z * c; xs[(i0 + 7) * 16 + m] = v1.w * c;
  }
  __syncthreads();

  // 16 rows x 128 cols, 2x4 register tile per thread
  const int jq = tid & 31, mg = tid >> 5;
  const int j0 = jq * 4, m0 = mg * 2;
  float acc[2][4] = {};
#pragma unroll 8
  for (int i = 0; i < DD; ++i) {
    float2 x2 = *reinterpret_cast<const float2*>(&xs[i * 16 + m0]);
    float4 w4 = *reinterpret_cast<const float4*>(wsrc + i * DD + j0);
    acc[0][0] += x2.x * w4.x; acc[0][1] += x2.x * w4.y;
    acc[0][2] += x2.x * w4.z; acc[0][3] += x2.x * w4.w;
    acc[1][0] += x2.y * w4.x; acc[1][1] += x2.y * w4.y;
    acc[1][2] += x2.y * w4.z; acc[1][3] += x2.y * w4.w;
  }

  if (is_edge) {
#pragma unroll
    for (int mi = 0; mi < 2; ++mi) {
      int mm = m0 + mi;
      if (mm < nrem) {
        float* orow = out + tqs[mm] * DD + j0;
        atomicAdd(&orow[0], acc[mi][0]);
        atomicAdd(&orow[1], acc[mi][1]);
        atomicAdd(&orow[2], acc[mi][2]);
        atomicAdd(&orow[3], acc[mi][3]);
      }
    }
  } else {
    float4 b4 = *reinterpret_cast<const float4*>(bias + j0);
#pragma unroll
    for (int mi = 0; mi < 2; ++mi) {
      float* orow = out + (n0 + m0 + mi) * DD + j0;
      atomicAdd(&orow[0], acc[mi][0] + b4.x);
      atomicAdd(&orow[1], acc[mi][1] + b4.y);
      atomicAdd(&orow[2], acc[mi][2] + b4.z);
      atomicAdd(&orow[3], acc[mi][3] + b4.w);
    }
  }
}

extern "C" void kernel_launch(void* const* d_in, const int* in_sizes, int n_in,
                              void* d_out, int out_size, void* d_ws, size_t ws_size,
                              hipStream_t stream) {
  const float* inp        = (const float*)d_in[0];
  const int*   deprel     = (const int*)d_in[1];
  const int*   edge_index = (const int*)d_in[2];
  const float* weight     = (const float*)d_in[3];
  const float* w_comp     = (const float*)d_in[4];
  const float* self_w     = (const float*)d_in[5];
  const float* bias       = (const float*)d_in[6];
  float* out = (float*)d_out;
  float* ws  = (float*)d_ws;

  // zero counts + relN cursors in one memset (contiguous)
  hipMemsetAsync(ws + CNT_OFF, 0, (size_t)(NNODES * RR + RR) * sizeof(float), stream);
  prep_kernel<<<2128, 256, 0, stream>>>(weight, w_comp, self_w, deprel, edge_index, ws, out);
  gemm_kernel<<<RR * ET + NNODES / 16, 256, 0, stream>>>(inp, edge_index, bias, ws, out);
}

// Round 3
// 129.104 us; speedup vs baseline: 1.1610x; 1.1001x over previous
//
#include <hip/hip_runtime.h>

#define NNODES 8192
#define NEDGES 16384
#define DD 128
#define RR 64
#define BB 16
#define CAP 512          // per-relation sorted-edge capacity
#define ET 11            // 32-edge tiles per relation (covers up to 352 edges/rel)
#define SELFT (NNODES/32) // 256 self tiles of 32 nodes

// ws layout (floats):
//   fw    : [FW_OFF,   +RR*DD*DD)     combined relation weights [64][128][128]
//   counts: [CNT_OFF,  +NNODES*RR)    per-(tgt,rel) edge counts (f32)
//   relN  : [RELN_OFF, +RR)           per-relation edge count / sort cursor (int)
//   swT   : [SWT_OFF,  +DD*DD)        self_weight transposed
//   sortE : [SORT_OFF, +RR*CAP)       edge ids, fixed-stride per-relation segments (int)
#define FW_OFF   0
#define CNT_OFF  (RR*DD*DD)
#define RELN_OFF (CNT_OFF + NNODES*RR)
#define SWT_OFF  (RELN_OFF + RR)
#define SORT_OFF (SWT_OFF + DD*DD)

// prep phases by blockIdx:
//   [0,1024)    : fw basis combination (float4)
//   [1024,1040) : swT transpose
//   [1040,1104) : edge counting-sort (LDS histogram) + per-(tgt,rel) count atomics
//   [1104,2128) : zero out[] (float4)
__global__ __launch_bounds__(256) void prep_kernel(
    const float* __restrict__ weight,      // [16,128,128]
    const float* __restrict__ w_comp,      // [64,16]
    const float* __restrict__ self_weight, // [128,128]
    const int* __restrict__ deprel,
    const int* __restrict__ edge_index,
    float* __restrict__ ws,
    float* __restrict__ out) {
  const int tid = threadIdx.x, bid = blockIdx.x;
  if (bid < 1024) {
    int g = bid * 256 + tid;          // float4 index, 4096 per relation
    int r = g >> 12;
    int ij4 = g & 4095;
    const float4* w4 = reinterpret_cast<const float4*>(weight);
    float4 acc = {0.f, 0.f, 0.f, 0.f};
#pragma unroll
    for (int b = 0; b < BB; ++b) {
      float c = w_comp[r * BB + b];
      float4 v = w4[b * 4096 + ij4];
      acc.x += c * v.x; acc.y += c * v.y; acc.z += c * v.z; acc.w += c * v.w;
    }
    reinterpret_cast<float4*>(ws + FW_OFF)[g] = acc;
  } else if (bid < 1040) {
    int idx = (bid - 1024) * 256 + tid;    // 0..4095
    int j = idx >> 5, i0 = (idx & 31) * 4;
    float4 v = *reinterpret_cast<const float4*>(self_weight + j * DD + i0);
    ws[SWT_OFF + (i0 + 0) * DD + j] = v.x;
    ws[SWT_OFF + (i0 + 1) * DD + j] = v.y;
    ws[SWT_OFF + (i0 + 2) * DD + j] = v.z;
    ws[SWT_OFF + (i0 + 3) * DD + j] = v.w;
  } else if (bid < 1104) {
    __shared__ int hist[RR];
    __shared__ int bse[RR];
    int e = (bid - 1040) * 256 + tid;
    int r = deprel[e];
    int t = edge_index[NEDGES + e];
    if (tid < RR) hist[tid] = 0;
    __syncthreads();
    atomicAdd(&hist[r], 1);
    atomicAdd(ws + CNT_OFF + t * RR + r, 1.0f);   // counts pre-zeroed by memset
    __syncthreads();
    int* relN = reinterpret_cast<int*>(ws + RELN_OFF);
    if (tid < RR) { bse[tid] = atomicAdd(&relN[tid], hist[tid]); hist[tid] = 0; }
    __syncthreads();
    int p = bse[r] + atomicAdd(&hist[r], 1);
    if (p < CAP) reinterpret_cast<int*>(ws + SORT_OFF)[r * CAP + p] = e;
  } else {
    int g = (bid - 1104) * 256 + tid;      // float4 index over out (262144 total)
    float4 z = {0.f, 0.f, 0.f, 0.f};
    reinterpret_cast<float4*>(out)[g] = z;
  }
}

// Unified streaming GEMM, XCD-aware block mapping:
//   physical block b -> XCD x = b%8 (dispatch round-robin heuristic), k = b/8.
//   k in [0, 8*ET)      : edge tile of relation r = x + 8*(k/ET)  -> all tiles of a
//                         relation land on ONE XCD, weight set per XCD = 512 KB (L2-hot)
//   k in [8*ET, 8*ET+32): self tile (32 nodes), weight = swT (shared, L2-hot)
// 32 rows x 128 cols per block, 4x4 register tile, weights streamed (no LDS stage).
__global__ __launch_bounds__(256, 4) void gemm_kernel(
    const float* __restrict__ inp,
    const int* __restrict__ edge_index,
    const float* __restrict__ bias,
    const float* __restrict__ ws,
    float* __restrict__ out) {
  __shared__ __align__(16) float xs[DD * 32];   // xs[i][m], pre-scaled; stride 32 = conflict-free
  __shared__ int tqs[32];
  __shared__ int sqs[32];
  __shared__ float cqs[32];
  const int tid = threadIdx.x;
  const int* relN  = reinterpret_cast<const int*>(ws + RELN_OFF);
  const int* sortE = reinterpret_cast<const int*>(ws + SORT_OFF);

  const int x = blockIdx.x & 7;      // XCD bin
  const int k = blockIdx.x >> 3;     // 0 .. 8*ET+31
  const bool is_edge = k < 8 * ET;
  int r = 0, base = 0, nrem = 32, n0 = 0;
  const float* wsrc;
  if (is_edge) {
    int q = k / ET;                  // 0..7
    r = x + 8 * q;
    base = (k - q * ET) * 32;
    int cnt = min(relN[r], ET * 32);
    if (base >= cnt) return;         // block-uniform early exit
    nrem = min(32, cnt - base);
    wsrc = ws + FW_OFF + r * DD * DD;
  } else {
    n0 = (x * 32 + (k - 8 * ET)) * 32;
    wsrc = ws + SWT_OFF;
  }

  if (tid < 32) {
    int s = 0, t = 0; float c = 0.f;
    if (is_edge) {
      if (tid < nrem) {
        int e = sortE[r * CAP + base + tid];
        s = edge_index[e];
        t = edge_index[NEDGES + e];
        c = 1.0f / ws[CNT_OFF + t * RR + r];
      }
    } else { s = n0 + tid; t = n0 + tid; c = 1.0f; }
    sqs[tid] = s; tqs[tid] = t; cqs[tid] = c;
  }
  __syncthreads();

  {
    int m = tid & 31, ih = tid >> 5;   // 32 lanes-per-node, 8 i-chunks of 16
    int s = sqs[m]; float c = cqs[m];
    const float4* srcp = reinterpret_cast<const float4*>(inp + s * DD + ih * 16);
#pragma unroll
    for (int kk = 0; kk < 4; ++kk) {
      float4 v = srcp[kk];
      int i = ih * 16 + kk * 4;
      xs[(i + 0) * 32 + m] = v.x * c;
      xs[(i + 1) * 32 + m] = v.y * c;
      xs[(i + 2) * 32 + m] = v.z * c;
      xs[(i + 3) * 32 + m] = v.w * c;
    }
  }
  __syncthreads();

  // 32 rows x 128 cols, 4x4 register tile per thread; weights streamed from L2
  const int jq = tid & 31, mg = tid >> 5;
  const int j0 = jq * 4, m0 = mg * 4;
  float acc[4][4] = {};
#pragma unroll 8
  for (int i = 0; i < DD; ++i) {
    float4 x4 = *reinterpret_cast<const float4*>(&xs[i * 32 + m0]);
    float4 w4 = *reinterpret_cast<const float4*>(wsrc + i * DD + j0);
    acc[0][0] += x4.x * w4.x; acc[0][1] += x4.x * w4.y; acc[0][2] += x4.x * w4.z; acc[0][3] += x4.x * w4.w;
    acc[1][0] += x4.y * w4.x; acc[1][1] += x4.y * w4.y; acc[1][2] += x4.y * w4.z; acc[1][3] += x4.y * w4.w;
    acc[2][0] += x4.z * w4.x; acc[2][1] += x4.z * w4.y; acc[2][2] += x4.z * w4.z; acc[2][3] += x4.z * w4.w;
    acc[3][0] += x4.w * w4.x; acc[3][1] += x4.w * w4.y; acc[3][2] += x4.w * w4.z; acc[3][3] += x4.w * w4.w;
  }

  if (is_edge) {
#pragma unroll
    for (int mi = 0; mi < 4; ++mi) {
      int mm = m0 + mi;
      if (mm < nrem) {
        float* orow = out + tqs[mm] * DD + j0;
        atomicAdd(&orow[0], acc[mi][0]);
        atomicAdd(&orow[1], acc[mi][1]);
        atomicAdd(&orow[2], acc[mi][2]);
        atomicAdd(&orow[3], acc[mi][3]);
      }
    }
  } else {
    float4 b4 = *reinterpret_cast<const float4*>(bias + j0);
#pragma unroll
    for (int mi = 0; mi < 4; ++mi) {
      float* orow = out + (n0 + m0 + mi) * DD + j0;
      atomicAdd(&orow[0], acc[mi][0] + b4.x);
      atomicAdd(&orow[1], acc[mi][1] + b4.y);
      atomicAdd(&orow[2], acc[mi][2] + b4.z);
      atomicAdd(&orow[3], acc[mi][3] + b4.w);
    }
  }
}

extern "C" void kernel_launch(void* const* d_in, const int* in_sizes, int n_in,
                              void* d_out, int out_size, void* d_ws, size_t ws_size,
                              hipStream_t stream) {
  const float* inp        = (const float*)d_in[0];
  const int*   deprel     = (const int*)d_in[1];
  const int*   edge_index = (const int*)d_in[2];
  const float* weight     = (const float*)d_in[3];
  const float* w_comp     = (const float*)d_in[4];
  const float* self_w     = (const float*)d_in[5];
  const float* bias       = (const float*)d_in[6];
  float* out = (float*)d_out;
  float* ws  = (float*)d_ws;

  // zero counts + relN cursors in one memset (contiguous)
  hipMemsetAsync(ws + CNT_OFF, 0, (size_t)(NNODES * RR + RR) * sizeof(float), stream);
  prep_kernel<<<2128, 256, 0, stream>>>(weight, w_comp, self_w, deprel, edge_index, ws, out);
  gemm_kernel<<<8 * (8 * ET + 32), 256, 0, stream>>>(inp, edge_index, bias, ws, out);
}

// Round 4
// 104.989 us; speedup vs baseline: 1.4276x; 1.2297x over previous
//
#include <hip/hip_runtime.h>

#define NNODES 8192
#define NEDGES 16384
#define DD 128
#define RR 64
#define BB 16
#define CAP 512          // per-relation sorted-edge segment stride (ints)
#define ET 11            // 32-edge tiles per relation (covers up to 352 edges/rel)
#define TCAP 20          // per-target incoming-edge capacity (Poisson(2); P(>20) ~ 1e-9)

// ws layout (floats):
//   fw    : [FW_OFF,    +RR*DD*DD)    combined relation weights [64][128][128]
//   counts: [CNT_OFF,   +NNODES*RR)   per-(tgt,rel) edge counts (f32)      \
//   relN  : [RELN_OFF,  +RR)          per-relation count / sort cursor (int)| one memset
//   tcnt  : [TCNT_OFF,  +NNODES)      per-target degree / cursor (int)     /
//   swT   : [SWT_OFF,   +DD*DD)       self_weight transposed
//   sortE : [SORT_OFF,  +RR*CAP)      edge ids, per-relation segments (int)
//   tlist : [TLIST_OFF, +NNODES*TCAP) per-target incoming edge ids (int)
//   pot   : [POT_OFF,   +NEDGES*DD)   per-edge scaled matvec result
//   potS  : [POTS_OFF,  +NNODES*DD)   per-node self-projection result
#define FW_OFF    0
#define CNT_OFF   (RR*DD*DD)
#define RELN_OFF  (CNT_OFF + NNODES*RR)
#define TCNT_OFF  (RELN_OFF + RR)
#define SWT_OFF   (TCNT_OFF + NNODES)
#define SORT_OFF  (SWT_OFF + DD*DD)
#define TLIST_OFF (SORT_OFF + RR*CAP)
#define POT_OFF   (TLIST_OFF + NNODES*TCAP)
#define POTS_OFF  (POT_OFF + NEDGES*DD)

// prep phases by blockIdx:
//   [0,1024)    : fw basis combination (float4, r uniform per block)
//   [1024,1040) : swT transpose
//   [1040,1104) : edge counting-sort + (t,r) count atomics + per-target list fill
__global__ __launch_bounds__(256) void prep_kernel(
    const float* __restrict__ weight,      // [16,128,128]
    const float* __restrict__ w_comp,      // [64,16]
    const float* __restrict__ self_weight, // [128,128]
    const int* __restrict__ deprel,
    const int* __restrict__ edge_index,
    float* __restrict__ ws) {
  const int tid = threadIdx.x, bid = blockIdx.x;
  if (bid < 1024) {
    int r = bid >> 4;                       // uniform per block -> scalar w_comp loads
    int ij4 = ((bid & 15) << 8) | tid;      // 0..4095 float4 index within relation
    const float* wc = w_comp + r * BB;
    const float4* w4 = reinterpret_cast<const float4*>(weight);
    float4 acc = {0.f, 0.f, 0.f, 0.f};
#pragma unroll
    for (int b = 0; b < BB; ++b) {
      float c = wc[b];
      float4 v = w4[b * 4096 + ij4];
      acc.x += c * v.x; acc.y += c * v.y; acc.z += c * v.z; acc.w += c * v.w;
    }
    reinterpret_cast<float4*>(ws + FW_OFF)[(r << 12) | ij4] = acc;
  } else if (bid < 1040) {
    int idx = (bid - 1024) * 256 + tid;     // 0..4095
    int j = idx >> 5, i0 = (idx & 31) * 4;
    float4 v = *reinterpret_cast<const float4*>(self_weight + j * DD + i0);
    ws[SWT_OFF + (i0 + 0) * DD + j] = v.x;
    ws[SWT_OFF + (i0 + 1) * DD + j] = v.y;
    ws[SWT_OFF + (i0 + 2) * DD + j] = v.z;
    ws[SWT_OFF + (i0 + 3) * DD + j] = v.w;
  } else {
    __shared__ int hist[RR];
    __shared__ int bse[RR];
    int e = (bid - 1040) * 256 + tid;
    int r = deprel[e];
    int t = edge_index[NEDGES + e];
    if (tid < RR) hist[tid] = 0;
    __syncthreads();
    atomicAdd(&hist[r], 1);
    atomicAdd(ws + CNT_OFF + t * RR + r, 1.0f);   // counts pre-zeroed by memset
    // per-target incoming list (gather CSR, fixed stride)
    {
      int* tcnt  = reinterpret_cast<int*>(ws + TCNT_OFF);
      int* tlist = reinterpret_cast<int*>(ws + TLIST_OFF);
      int p = atomicAdd(&tcnt[t], 1);
      if (p < TCAP) tlist[t * TCAP + p] = e;
    }
    __syncthreads();
    int* relN = reinterpret_cast<int*>(ws + RELN_OFF);
    if (tid < RR) { bse[tid] = atomicAdd(&relN[tid], hist[tid]); hist[tid] = 0; }
    __syncthreads();
    int p = bse[r] + atomicAdd(&hist[r], 1);
    if (p < CAP) reinterpret_cast<int*>(ws + SORT_OFF)[r * CAP + p] = e;
  }
}

// Streaming GEMM -> dense per-edge/per-node result buffers, PLAIN stores (no atomics).
// XCD-aware mapping: block b -> x = b%8, k = b/8.
//   k in [0, 8*ET)      : edge tile of relation r = x + 8*(k/ET) (rel bound to one XCD)
//   k in [8*ET, 8*ET+32): self tile of 32 nodes
__global__ __launch_bounds__(256, 4) void pot_kernel(
    const float* __restrict__ inp,
    const int* __restrict__ edge_index,
    float* __restrict__ ws) {
  __shared__ __align__(16) float xs[DD * 32];   // xs[i][m], pre-scaled; stride 32
  __shared__ int eqs[32];
  __shared__ int sqs[32];
  __shared__ float cqs[32];
  const int tid = threadIdx.x;
  const int* relN  = reinterpret_cast<const int*>(ws + RELN_OFF);
  const int* sortE = reinterpret_cast<const int*>(ws + SORT_OFF);
  float* pot  = ws + POT_OFF;
  float* potS = ws + POTS_OFF;

  const int x = blockIdx.x & 7;
  const int k = blockIdx.x >> 3;
  const bool is_edge = k < 8 * ET;
  int r = 0, base = 0, nrem = 32, n0 = 0;
  const float* wsrc;
  if (is_edge) {
    int q = k / ET;
    r = x + 8 * q;
    base = (k - q * ET) * 32;
    int cnt = min(relN[r], ET * 32);
    if (base >= cnt) return;              // block-uniform early exit
    nrem = min(32, cnt - base);
    wsrc = ws + FW_OFF + r * DD * DD;
  } else {
    n0 = (x * 32 + (k - 8 * ET)) * 32;
    wsrc = ws + SWT_OFF;
  }

  if (tid < 32) {
    int e = 0, s = 0; float c = 0.f;
    if (is_edge) {
      if (tid < nrem) {
        e = sortE[r * CAP + base + tid];
        s = edge_index[e];
        int t = edge_index[NEDGES + e];
        c = 1.0f / ws[CNT_OFF + t * RR + r];
      }
    } else { s = n0 + tid; c = 1.0f; }
    eqs[tid] = e; sqs[tid] = s; cqs[tid] = c;
  }
  __syncthreads();

  {
    int m = tid & 31, ih = tid >> 5;
    int s = sqs[m]; float c = cqs[m];
    const float4* srcp = reinterpret_cast<const float4*>(inp + s * DD + ih * 16);
#pragma unroll
    for (int kk = 0; kk < 4; ++kk) {
      float4 v = srcp[kk];
      int i = ih * 16 + kk * 4;
      xs[(i + 0) * 32 + m] = v.x * c;
      xs[(i + 1) * 32 + m] = v.y * c;
      xs[(i + 2) * 32 + m] = v.z * c;
      xs[(i + 3) * 32 + m] = v.w * c;
    }
  }
  __syncthreads();

  const int jq = tid & 31, mg = tid >> 5;
  const int j0 = jq * 4, m0 = mg * 4;
  float acc[4][4] = {};
#pragma unroll 8
  for (int i = 0; i < DD; ++i) {
    float4 x4 = *reinterpret_cast<const float4*>(&xs[i * 32 + m0]);
    float4 w4 = *reinterpret_cast<const float4*>(wsrc + i * DD + j0);
    acc[0][0] += x4.x * w4.x; acc[0][1] += x4.x * w4.y; acc[0][2] += x4.x * w4.z; acc[0][3] += x4.x * w4.w;
    acc[1][0] += x4.y * w4.x; acc[1][1] += x4.y * w4.y; acc[1][2] += x4.y * w4.z; acc[1][3] += x4.y * w4.w;
    acc[2][0] += x4.z * w4.x; acc[2][1] += x4.z * w4.y; acc[2][2] += x4.z * w4.z; acc[2][3] += x4.z * w4.w;
    acc[3][0] += x4.w * w4.x; acc[3][1] += x4.w * w4.y; acc[3][2] += x4.w * w4.z; acc[3][3] += x4.w * w4.w;
  }

  if (is_edge) {
#pragma unroll
    for (int mi = 0; mi < 4; ++mi) {
      int mm = m0 + mi;
      if (mm < nrem) {
        float4 o = {acc[mi][0], acc[mi][1], acc[mi][2], acc[mi][3]};
        *reinterpret_cast<float4*>(pot + eqs[mm] * DD + j0) = o;
      }
    }
  } else {
#pragma unroll
    for (int mi = 0; mi < 4; ++mi) {
      float4 o = {acc[mi][0], acc[mi][1], acc[mi][2], acc[mi][3]};
      *reinterpret_cast<float4*>(potS + (n0 + m0 + mi) * DD + j0) = o;
    }
  }
}

// out[t] = bias + potS[t] + sum_{e in tlist[t]} pot[e].  8 targets/block, 32 lanes each.
__global__ __launch_bounds__(256) void gather_kernel(
    const float* __restrict__ bias,
    const float* __restrict__ ws,
    float* __restrict__ out) {
  const int tid = threadIdx.x;
  const int t = blockIdx.x * 8 + (tid >> 5);
  const int j0 = (tid & 31) * 4;
  const int* tcnt  = reinterpret_cast<const int*>(ws + TCNT_OFF);
  const int* tlist = reinterpret_cast<const int*>(ws + TLIST_OFF) + t * TCAP;
  const float* pot  = ws + POT_OFF;
  const float* potS = ws + POTS_OFF;

  float4 s = *reinterpret_cast<const float4*>(potS + t * DD + j0);
  float4 b4 = *reinterpret_cast<const float4*>(bias + j0);
  s.x += b4.x; s.y += b4.y; s.z += b4.z; s.w += b4.w;
  int deg = tcnt[t];
  deg = min(deg, TCAP);
#pragma unroll 4
  for (int d = 0; d < deg; ++d) {
    int e = tlist[d];
    float4 p = *reinterpret_cast<const float4*>(pot + e * DD + j0);
    s.x += p.x; s.y += p.y; s.z += p.z; s.w += p.w;
  }
  *reinterpret_cast<float4*>(out + t * DD + j0) = s;
}

extern "C" void kernel_launch(void* const* d_in, const int* in_sizes, int n_in,
                              void* d_out, int out_size, void* d_ws, size_t ws_size,
                              hipStream_t stream) {
  const float* inp        = (const float*)d_in[0];
  const int*   deprel     = (const int*)d_in[1];
  const int*   edge_index = (const int*)d_in[2];
  const float* weight     = (const float*)d_in[3];
  const float* w_comp     = (const float*)d_in[4];
  const float* self_w     = (const float*)d_in[5];
  const float* bias       = (const float*)d_in[6];
  float* out = (float*)d_out;
  float* ws  = (float*)d_ws;

  // zero counts + relN + tcnt in one contiguous memset
  hipMemsetAsync(ws + CNT_OFF, 0,
                 (size_t)(NNODES * RR + RR + NNODES) * sizeof(float), stream);
  prep_kernel<<<1104, 256, 0, stream>>>(weight, w_comp, self_w, deprel, edge_index, ws);
  pot_kernel<<<8 * (8 * ET + 32), 256, 0, stream>>>(inp, edge_index, ws);
  gather_kernel<<<NNODES / 8, 256, 0, stream>>>(bias, ws, out);
}